// Round 1
// baseline (127.021 us; speedup 1.0000x reference)
//
#include <hip/hip_runtime.h>

#define T_STEPS 128
#define DIM 1024
#define ODE_UNFOLDS 6
#define EPS 1e-8f
#define L2E 1.44269504088896340736f

__device__ __forceinline__ float fexp2(float x) { return __builtin_amdgcn_exp2f(x); }
__device__ __forceinline__ float frcp(float x)  { return __builtin_amdgcn_rcpf(x); }

__device__ __forceinline__ float softplus_init(float x) {
  // init-only (once per thread); x in (0,1] here so no overflow concerns
  return log2f(1.0f + exp2f(x * L2E)) * (1.0f / L2E);
}

// swap adjacent lane pairs (0<->1, 2<->3, ...): v_mov_b32_dpp quad_perm:[1,0,3,2]
__device__ __forceinline__ float swap_adj(float x) {
  int y = __builtin_amdgcn_mov_dpp(__float_as_int(x), 0xB1, 0xF, 0xF, true);
  return __int_as_float(y);
}

__global__ __launch_bounds__(256) void memcell_kernel(
    const float* __restrict__ inputs,      // (B,T,DIM)
    const float* __restrict__ gleak,       // (U)
    const float* __restrict__ vleak,       // (U)
    const float* __restrict__ cm,          // (U)
    const float* __restrict__ w,           // (U,2)
    const float* __restrict__ sigma,       // (U,2)
    const float* __restrict__ mu,          // (U,2)
    const float* __restrict__ erev,        // (U,2)
    const float* __restrict__ sens_w,      // (U)
    const float* __restrict__ sens_sigma,  // (U)
    const float* __restrict__ sens_mu,     // (U)
    const float* __restrict__ sens_erev,   // (U)
    const float* __restrict__ input_w,     // (DIM)
    const float* __restrict__ input_b,     // (DIM)
    const float* __restrict__ output_w,    // (DIM)
    const float* __restrict__ output_b,    // (DIM)
    float* __restrict__ out)               // (B,DIM)
{
  const int tid  = blockIdx.x * blockDim.x + threadIdx.x;  // [0, B*U)
  const int p    = tid >> 1;          // chain index: b*DIM + col
  const int half = tid & 1;           // 0: unit=col, 1: unit=col+DIM
  const int b    = p >> 10;           // DIM == 1024
  const int col  = p & (DIM - 1);
  const int u    = col + (half << 10);

  // ---- per-thread constants (loaded/derived once) ----
  const float spw0  = softplus_init(w[2*u]);
  const float spw1  = softplus_init(w[2*u+1]);
  const float e0    = erev[2*u];
  const float e1    = erev[2*u+1];
  const float spw0e = spw0 * e0;
  const float spw1e = spw1 * e1;
  const float sg0   = sigma[2*u],  sg1 = sigma[2*u+1];
  const float mu0   = mu[2*u],     mu1 = mu[2*u+1];
  // sigmoid((v-mu)*sg) = 1/(1 + exp2(fma(v, -sg*L2E, mu*sg*L2E)))
  const float negA0 = -sg0 * L2E,  B0c = mu0 * sg0 * L2E;
  const float negA1 = -sg1 * L2E,  B1c = mu1 * sg1 * L2E;
  const float gl    = softplus_init(gleak[u]);
  const float glv   = gl * vleak[u];
  const float cmt   = softplus_init(cm[u]) * (float)ODE_UNFOLDS;
  const float dbase = cmt + gl + EPS;
  const float spsw  = softplus_init(sens_w[u]);
  const float ssg   = sens_sigma[u];
  const float smu   = sens_mu[u];
  const float negAs = -ssg * L2E,  Bsc = smu * ssg * L2E;
  const float serev = sens_erev[u];
  const float iw    = input_w[col];
  const float ib    = input_b[col];

  // combined constants for the t-polynomial forms
  const float spw01 = spw0 + spw1;          // deno const part (w/ ds added per step)
  const float L0    = spw0e + spw1e;        // nume const part (w/ numerN added per unfold)
  // partner's synapse-1 exp-arg constants (each lane computes the partner's t1
  // locally from its OWN v, using the partner's params; result swapped post-exp2)
  const float negA1p = swap_adj(negA1);
  const float B1p    = swap_adj(B1c);

  const float* xp = inputs + ((size_t)b * T_STEPS) * DIM + col;

  // 4-deep x prefetch pipeline (hides HBM latency at 1 wave/SIMD)
  float xs0 = xp[0 * DIM];
  float xs1 = xp[1 * DIM];
  float xs2 = xp[2 * DIM];
  float xs3 = xp[3 * DIM];

  // state carried as a rational pair: v == nume * r (r = rcp of last deno).
  // init v=0  ->  nume=0, r=1 (any finite r works since nume==0)
  float nume = 0.0f;
  float r    = 1.0f;

  for (int tb = 0; tb < T_STEPS; tb += 4) {
    const float c0 = xs0, c1 = xs1, c2 = xs2, c3 = xs3;
    if (tb + 4 < T_STEPS) {
      const float* nx = xp + (size_t)(tb + 4) * DIM;
      xs0 = nx[0 * DIM];
      xs1 = nx[1 * DIM];
      xs2 = nx[2 * DIM];
      xs3 = nx[3 * DIM];
    }

    // hoist ALL per-step (v-independent) sensory work for the 4 steps:
    // these exp2/rcp + adds are off the recurrence chain and fill stall slots.
    float nsv[4], dsv[4], K0v[4], K1v[4], K2v[4];
    #pragma unroll
    for (int j = 0; j < 4; ++j) {
      const float xr = (j == 0) ? c0 : (j == 1) ? c1 : (j == 2) ? c2 : c3;
      const float x  = fmaf(xr, iw, ib);
      const float ts = fexp2(fmaf(x, negAs, Bsc));
      const float s  = spsw * frcp(1.0f + ts);
      nsv[j] = fmaf(s, serev, glv);   // glv + num_s
      const float ds = dbase + s;     // cmt + gl + eps + den_s
      dsv[j] = ds;
      K0v[j] = ds + spw01;            // deno: const coeff
      K1v[j] = ds + spw1;             // deno: t0 coeff
      K2v[j] = ds + spw0;             // deno: t1 coeff
    }

    #pragma unroll
    for (int j = 0; j < 4; ++j) {
      const float ns = nsv[j], ds = dsv[j];
      const float K0 = K0v[j], K1 = K1v[j], K2 = K2v[j];
      #pragma unroll
      for (int k = 0; k < ODE_UNFOLDS; ++k) {
        // ---- off-chain pre-folds (depend on nume, ready long before r) ----
        const float cn  = cmt  * nume;
        const float nn0 = nume * negA0;
        const float nn1 = nume * negA1p;
        // ---- chain: r -> z-fma -> exp2 ----
        const float z0  = fmaf(nn0, r, B0c);   // = v*negA0 + B0c
        const float z1p = fmaf(nn1, r, B1p);   // partner's t1 arg, from MY v
        const float t0  = fexp2(z0);
        const float tp  = fexp2(z1p);
        const float numerN = fmaf(cn, r, ns);  // = cmt*v + ns (off-chain)
        const float t1  = swap_adj(tp);        // DPP parallel to A1-fma, off-chain
        // ---- deno = K0 + K1*t0 + K2*t1 + ds*t0*t1 (3-fma tree, depth 12) ----
        const float A1   = fmaf(K1, t0, K0);
        const float m    = t0 * t1;
        const float X2   = fmaf(K2, t1, A1);
        const float deno = fmaf(ds, m, X2);
        // ---- nume' = numerN*(1+t0+t1+m) + spw1e*t0 + spw0e*t1 + L0 ----
        const float base = numerN + L0;
        const float g0   = numerN + spw1e;
        const float g1   = numerN + spw0e;
        float na = fmaf(g0, t0, base);
        na       = fmaf(g1, t1, na);
        nume     = fmaf(numerN, m, na);
        r        = frcp(deno);
      }
    }
  }

  if (half == 0) {
    const float v = nume * r;
    out[(size_t)b * DIM + col] = fmaf(v, output_w[col], output_b[col]);
  }
}

extern "C" void kernel_launch(void* const* d_in, const int* in_sizes, int n_in,
                              void* d_out, int out_size, void* d_ws, size_t ws_size,
                              hipStream_t stream) {
  const float* inputs      = (const float*)d_in[0];
  const float* gleak       = (const float*)d_in[1];
  const float* vleak       = (const float*)d_in[2];
  const float* cm          = (const float*)d_in[3];
  const float* w           = (const float*)d_in[4];
  const float* sigma       = (const float*)d_in[5];
  const float* mu          = (const float*)d_in[6];
  const float* erev        = (const float*)d_in[7];
  const float* sens_w      = (const float*)d_in[8];
  const float* sens_sigma  = (const float*)d_in[9];
  const float* sens_mu     = (const float*)d_in[10];
  const float* sens_erev   = (const float*)d_in[11];
  const float* input_w     = (const float*)d_in[12];
  const float* input_b     = (const float*)d_in[13];
  const float* output_w    = (const float*)d_in[14];
  const float* output_b    = (const float*)d_in[15];

  const int B = in_sizes[0] / (T_STEPS * DIM);   // 32
  const int U = 2 * DIM;
  const int total_threads = B * U;               // 65536
  dim3 block(256);
  dim3 grid(total_threads / 256);                // 256 blocks -> 1 block/CU

  memcell_kernel<<<grid, block, 0, stream>>>(
      inputs, gleak, vleak, cm, w, sigma, mu, erev,
      sens_w, sens_sigma, sens_mu, sens_erev,
      input_w, input_b, output_w, output_b, (float*)d_out);
}

// Round 2
// 119.300 us; speedup vs baseline: 1.0647x; 1.0647x over previous
//
#include <hip/hip_runtime.h>

#define T_STEPS 128
#define DIM 1024
#define ODE_UNFOLDS 6
#define EPS 1e-8f
#define L2E 1.44269504088896340736f

__device__ __forceinline__ float fexp2(float x) { return __builtin_amdgcn_exp2f(x); }
__device__ __forceinline__ float frcp(float x)  { return __builtin_amdgcn_rcpf(x); }

__device__ __forceinline__ float softplus_init(float x) {
  // init-only (once per thread); x in (0,1] here so no overflow concerns
  return log2f(1.0f + exp2f(x * L2E)) * (1.0f / L2E);
}

// swap adjacent lane pairs (0<->1, 2<->3, ...): v_mov_b32_dpp quad_perm:[1,0,3,2]
// full-rate VALU, no LDS/lgkm latency on the recurrence critical path
__device__ __forceinline__ float swap_adj(float x) {
  int y = __builtin_amdgcn_mov_dpp(__float_as_int(x), 0xB1, 0xF, 0xF, true);
  return __int_as_float(y);
}

__global__ __launch_bounds__(256) void memcell_kernel(
    const float* __restrict__ inputs,      // (B,T,DIM)
    const float* __restrict__ gleak,       // (U)
    const float* __restrict__ vleak,       // (U)
    const float* __restrict__ cm,          // (U)
    const float* __restrict__ w,           // (U,2)
    const float* __restrict__ sigma,       // (U,2)
    const float* __restrict__ mu,          // (U,2)
    const float* __restrict__ erev,        // (U,2)
    const float* __restrict__ sens_w,      // (U)
    const float* __restrict__ sens_sigma,  // (U)
    const float* __restrict__ sens_mu,     // (U)
    const float* __restrict__ sens_erev,   // (U)
    const float* __restrict__ input_w,     // (DIM)
    const float* __restrict__ input_b,     // (DIM)
    const float* __restrict__ output_w,    // (DIM)
    const float* __restrict__ output_b,    // (DIM)
    float* __restrict__ out)               // (B,DIM)
{
  const int tid  = blockIdx.x * blockDim.x + threadIdx.x;  // [0, B*U)
  const int p    = tid >> 1;          // chain index: b*DIM + col
  const int half = tid & 1;           // 0: unit=col, 1: unit=col+DIM
  const int b    = p >> 10;           // DIM == 1024
  const int col  = p & (DIM - 1);
  const int u    = col + (half << 10);

  // ---- per-thread constants (loaded/derived once) ----
  const float spw0  = softplus_init(w[2*u]);
  const float spw1  = softplus_init(w[2*u+1]);
  const float e0    = erev[2*u];
  const float e1    = erev[2*u+1];
  const float spw0e = spw0 * e0;
  const float spw1e = spw1 * e1;
  const float sg0   = sigma[2*u],  sg1 = sigma[2*u+1];
  const float mu0   = mu[2*u],     mu1 = mu[2*u+1];
  // sigmoid((v-mu)*sg) = 1/(1 + exp2(fma(v, -sg*L2E, mu*sg*L2E)))
  const float negA0 = -sg0 * L2E,  B0c = mu0 * sg0 * L2E;
  const float negA1 = -sg1 * L2E,  B1c = mu1 * sg1 * L2E;
  const float gl    = softplus_init(gleak[u]);
  const float glv   = gl * vleak[u];
  const float cmt   = softplus_init(cm[u]) * (float)ODE_UNFOLDS;
  const float dbase = cmt + gl + EPS;
  const float spsw  = softplus_init(sens_w[u]);
  const float ssg   = sens_sigma[u];
  const float smu   = sens_mu[u];
  const float negAs = -ssg * L2E,  Bsc = smu * ssg * L2E;
  const float serev = sens_erev[u];
  const float iw    = input_w[col];
  const float ib    = input_b[col];

  // partner's synapse-1 exp-arg constants: each lane computes the partner's t1
  // locally from its OWN v (same-cost fma), result swapped AFTER exp2 so the
  // DPP overlaps the own-path a0/p computation instead of heading the chain.
  const float negA1p = swap_adj(negA1);
  const float B1p    = swap_adj(B1c);

  const float* xp = inputs + ((size_t)b * T_STEPS) * DIM + col;

  // 4-deep x prefetch pipeline (hides HBM latency at 1 wave/SIMD)
  float xs0 = xp[0 * DIM];
  float xs1 = xp[1 * DIM];
  float xs2 = xp[2 * DIM];
  float xs3 = xp[3 * DIM];

  float v = 0.0f;

  for (int tb = 0; tb < T_STEPS; tb += 4) {
    const float c0 = xs0, c1 = xs1, c2 = xs2, c3 = xs3;
    if (tb + 4 < T_STEPS) {
      const float* nx = xp + (size_t)(tb + 4) * DIM;
      xs0 = nx[0 * DIM];
      xs1 = nx[1 * DIM];
      xs2 = nx[2 * DIM];
      xs3 = nx[3 * DIM];
    }
    #pragma unroll
    for (int j = 0; j < 4; ++j) {
      const float xr = (j == 0) ? c0 : (j == 1) ? c1 : (j == 2) ? c2 : c3;
      const float x  = fmaf(xr, iw, ib);
      // sensory synapse (once per step)
      const float ts    = fexp2(fmaf(x, negAs, Bsc));
      const float s     = spsw * frcp(1.0f + ts);
      const float ns    = fmaf(s, serev, glv);   // glv + num_s
      const float ds    = dbase + s;             // cmt + gl + eps + den_s
      const float dspw0 = ds + spw0;             // for the folded p-fma
      #pragma unroll
      for (int k = 0; k < ODE_UNFOLDS; ++k) {
        // multiply num & den through by a0*a1 -> one rcp per unfold.
        //   nume = a1*(numerN*a0 + spw0e) + spw1e*a0
        //   deno = a1*(ds*a0 + spw0)     + spw1 *a0
        // with the deno "+1" folded: ds*a0 + spw0 = fma(ds, t0, ds+spw0)
        const float z0  = fmaf(v, negA0,  B0c);
        const float z1p = fmaf(v, negA1p, B1p);   // partner's t1 arg, from MY v
        const float t0  = fexp2(z0);
        const float tp  = fexp2(z1p);
        const float t1  = swap_adj(tp);           // DPP off own path
        const float a0  = 1.0f + t0;
        const float numerN = fmaf(cmt, v, ns);    // off-chain
        const float q   = fmaf(numerN, a0, spw0e);
        const float e_t = spw1e * a0;
        const float p   = fmaf(ds, t0, dspw0);    // chain: t0 -> p (a0-add skipped)
        const float s_t = spw1 * a0;
        const float a1  = 1.0f + t1;
        const float nume = fmaf(a1, q, e_t);
        const float deno = fmaf(a1, p, s_t);
        const float r   = frcp(deno);
        v = nume * r;
      }
    }
  }

  if (half == 0) {
    out[(size_t)b * DIM + col] = fmaf(v, output_w[col], output_b[col]);
  }
}

extern "C" void kernel_launch(void* const* d_in, const int* in_sizes, int n_in,
                              void* d_out, int out_size, void* d_ws, size_t ws_size,
                              hipStream_t stream) {
  const float* inputs      = (const float*)d_in[0];
  const float* gleak       = (const float*)d_in[1];
  const float* vleak       = (const float*)d_in[2];
  const float* cm          = (const float*)d_in[3];
  const float* w           = (const float*)d_in[4];
  const float* sigma       = (const float*)d_in[5];
  const float* mu          = (const float*)d_in[6];
  const float* erev        = (const float*)d_in[7];
  const float* sens_w      = (const float*)d_in[8];
  const float* sens_sigma  = (const float*)d_in[9];
  const float* sens_mu     = (const float*)d_in[10];
  const float* sens_erev   = (const float*)d_in[11];
  const float* input_w     = (const float*)d_in[12];
  const float* input_b     = (const float*)d_in[13];
  const float* output_w    = (const float*)d_in[14];
  const float* output_b    = (const float*)d_in[15];

  const int B = in_sizes[0] / (T_STEPS * DIM);   // 32
  const int U = 2 * DIM;
  const int total_threads = B * U;               // 65536
  dim3 block(256);
  dim3 grid(total_threads / 256);                // 256 blocks -> 1 block/CU

  memcell_kernel<<<grid, block, 0, stream>>>(
      inputs, gleak, vleak, cm, w, sigma, mu, erev,
      sens_w, sens_sigma, sens_mu, sens_erev,
      input_w, input_b, output_w, output_b, (float*)d_out);
}